// Round 13
// baseline (160.138 us; speedup 1.0000x reference)
//
#include <hip/hip_runtime.h>

#define NPTS  65536
#define KNB   32
#define KPn   15
#define CIN   64
#define COUT  128
#define MPTS  32            // points per block (2 MFMA M-tiles)
#define THREADS 256
#define WSTRIDE 968         // wl row stride in bf16 elems (960 + 8 pad)
#define BCAP  48            // bucket cap per point (near-origin bursts)
#define RCAP  160           // radius-candidate cap (mean ~61 for 1024 slots)
#define NTILE 8             // 128 cols / 16
#define KSTEPS 30           // 960 / 32
#define WELEMS (NTILE * KSTEPS * 64 * 8)    // 122880 bf16 elements

typedef __attribute__((ext_vector_type(8))) short short8;
typedef __attribute__((ext_vector_type(4))) float f32x4;

__device__ __forceinline__ unsigned int f2bf(float f) {
    union { float f; unsigned int i; } v; v.f = f;
    return (v.i + 0x7fffu + ((v.i >> 16) & 1u)) >> 16;   // RNE
}

// ---- prep: pack weights into MFMA B-fragment order (permuted K) + kpq/R2 ----
__global__ void wtrans_kernel(const float* __restrict__ w,
                              const float* __restrict__ kpts,
                              unsigned short* __restrict__ wTf,
                              float4* __restrict__ kpq_out) {  // [16]: 15 kpq + {R2}
    const int d = blockIdx.x * 256 + threadIdx.x;
    if (d < WELEMS) {
        const int j    = d & 7;
        const int lane = (d >> 3) & 63;
        const int ks   = (d >> 9) % KSTEPS;
        const int t    = d / (KSTEPS * 512);
        const int f    = ks * 32 + (lane >> 4) * 8 + j;
        const int cg   = f / 120;
        const int rem  = f - cg * 120;
        const int orig = (rem >> 3) * 64 + cg * 8 + (rem & 7);
        const int n    = t * 16 + (lane & 15);
        wTf[d] = (unsigned short)f2bf(w[(size_t)orig * COUT + n]);
    }
    if (blockIdx.x == 0 && threadIdx.x < 16) {
        const int k = threadIdx.x;
        if (k < KPn) {
            const float x = kpts[k * 3 + 0];
            const float y = kpts[k * 3 + 1];
            const float z = kpts[k * 3 + 2];
            kpq_out[k] = make_float4(x, y, z, x * x + y * y + z * z);
        } else {
            float mx = 0.f;
            for (int i = 0; i < KPn; ++i) {
                const float x = kpts[i * 3 + 0];
                const float y = kpts[i * 3 + 1];
                const float z = kpts[i * 3 + 2];
                mx = fmaxf(mx, x * x + y * y + z * z);
            }
            const float R = 0.1f + sqrtf(mx);
            kpq_out[15] = make_float4(R * R, 0.f, 0.f, 0.f);
        }
    }
}

__global__ __launch_bounds__(THREADS, 2) void kpconv_kernel(
    const float* __restrict__ pos,         // [N,3] f32
    const float* __restrict__ feats,       // [N,64] f32
    const unsigned short* __restrict__ wTf,// fragment-packed bf16 weights
    const float4* __restrict__ kpq_in,     // [16] precomputed kpq + R2
    const int*   __restrict__ neighbors,   // [N,32] int32
    float*       __restrict__ out)         // [N,128] f32
{
    __shared__ unsigned short wl[MPTS * WSTRIDE];  // 61952 B (permuted-K bf16)
    __shared__ unsigned int  bpk[MPTS][BCAP];      // 6 KB: (nb<<16)|(k<<12)|w12
    __shared__ int    bcnt[MPTS];
    __shared__ float  cposf[MPTS * 3];
    __shared__ float4 kpq[KPn];
    __shared__ float  rlx[RCAP], rly[RCAP], rlz[RCAP], rld[RCAP];
    __shared__ unsigned int rsl[RCAP];             // (p<<16) | nb
    __shared__ int    nact;
    __shared__ float  R2s;

    const int tid = threadIdx.x;
    const int n0  = blockIdx.x * MPTS;

    // ---- init ----
    if (tid < KPn) kpq[tid] = kpq_in[tid];
    if (tid == KPn) R2s = kpq_in[15].x;
    if (tid < MPTS) bcnt[tid] = 0;
    if (tid == THREADS - 1) nact = 0;
    if (tid < MPTS * 3) cposf[tid] = pos[(size_t)n0 * 3 + tid];
    __syncthreads();

    // ---- stage 1a-compact: radius filter over 1024 (p,j) slots ----
    {
        const float R2 = R2s;
        #pragma unroll
        for (int it = 0; it < MPTS * KNB / THREADS; ++it) {
            const int s  = tid + it * THREADS;
            const int p  = s >> 5;
            const int nb = neighbors[(size_t)n0 * KNB + s];
            const float rx = pos[(size_t)nb * 3 + 0] - cposf[p * 3 + 0];
            const float ry = pos[(size_t)nb * 3 + 1] - cposf[p * 3 + 1];
            const float rz = pos[(size_t)nb * 3 + 2] - cposf[p * 3 + 2];
            const float d2r = rx * rx + ry * ry + rz * rz;
            if (d2r < R2) {
                const int idx = atomicAdd(&nact, 1);
                if (idx < RCAP) {
                    rlx[idx] = rx; rly[idx] = ry; rlz[idx] = rz; rld[idx] = d2r;
                    rsl[idx] = ((unsigned int)p << 16) | (unsigned int)nb;
                }
            }
        }
    }
    __syncthreads();

    // ---- stage 1a-k: exact kernel-point test over candidates ----
    {
        const int E = min(nact, RCAP);
        for (int u = tid; u < E * 16; u += THREADS) {
            const int e = u >> 4;
            const int k = u & 15;
            if (k < KPn) {
                const float4 kp  = kpq[k];
                const float  d2r = rld[e];
                const float dot = rlx[e] * kp.x + rly[e] * kp.y + rlz[e] * kp.z;
                if (dot > 0.5f * (d2r - 0.01f + kp.w)) {
                    const float d2 = fmaxf(d2r - 2.f * dot + kp.w, 0.f);
                    const float w  = 1.0f - 10.0f * sqrtf(d2);
                    const unsigned int wq = (unsigned int)(w * 4095.0f + 0.5f);
                    const unsigned int sl = rsl[e];
                    const int p = (int)(sl >> 16);
                    const int idx = atomicAdd(&bcnt[p], 1);
                    if (idx < BCAP)
                        bpk[p][idx] = ((sl & 0xFFFFu) << 16) |
                                      ((unsigned int)k << 12) | wq;
                }
            }
        }
    }
    __syncthreads();

    // ---- stage 1b: ownership accumulation, 8 channels per work item ----
    #pragma unroll
    for (int it = 0; it < 16; ++it) {
        const int wi = tid + it * THREADS;        // 0..4095
        const int cg = wi & 7;
        const int k  = (wi >> 3) & 15;
        const int p  = wi >> 7;                   // 0..31
        if (k < KPn) {
            float a0=0.f,a1=0.f,a2=0.f,a3=0.f,a4=0.f,a5=0.f,a6=0.f,a7=0.f;
            const int cnt = min(bcnt[p], BCAP);
            for (int e = 0; e < cnt; ++e) {
                const unsigned int id = bpk[p][e];
                if (((id >> 12) & 15u) == (unsigned int)k) {
                    const float wv = (float)(id & 4095u) * (1.0f / 4095.0f);
                    const float* fr = feats + (size_t)(id >> 16) * CIN + cg * 8;
                    const float4 f0 = *(const float4*)fr;
                    const float4 f1 = *(const float4*)(fr + 4);
                    a0 += wv * f0.x; a1 += wv * f0.y; a2 += wv * f0.z; a3 += wv * f0.w;
                    a4 += wv * f1.x; a5 += wv * f1.y; a6 += wv * f1.z; a7 += wv * f1.w;
                }
            }
            uint4 u;
            u.x = f2bf(a0) | (f2bf(a1) << 16);
            u.y = f2bf(a2) | (f2bf(a3) << 16);
            u.z = f2bf(a4) | (f2bf(a5) << 16);
            u.w = f2bf(a6) | (f2bf(a7) << 16);
            *(uint4*)(wl + p * WSTRIDE + cg * 120 + k * 8) = u;   // permuted-K
        }
    }
    __syncthreads();

    // ---- stage 2: out[32][128] = wl @ W, 32x32 output tile per wave ----
    // wave w: N-tiles {2w, 2w+1}, M-tiles {0,1}. 2 A-reads + 2 B-loads -> 4 MFMA.
    {
        const int wave = tid >> 6;
        const int lane = tid & 63;
        const int m    = lane & 15;
        const int q    = lane >> 4;

        f32x4 acc00 = {0.f,0.f,0.f,0.f};   // M0 x N-tile 2w
        f32x4 acc01 = {0.f,0.f,0.f,0.f};   // M0 x N-tile 2w+1
        f32x4 acc10 = {0.f,0.f,0.f,0.f};   // M1 x N-tile 2w
        f32x4 acc11 = {0.f,0.f,0.f,0.f};   // M1 x N-tile 2w+1

        const unsigned short* a0p = wl + m * WSTRIDE + q * 8;
        const unsigned short* a1p = a0p + 16 * WSTRIDE;
        const short8* bp0 = (const short8*)wTf + (size_t)(2 * wave) * KSTEPS * 64 + lane;
        const short8* bp1 = bp0 + (size_t)KSTEPS * 64;

        #pragma unroll 5
        for (int ks = 0; ks < KSTEPS; ++ks, a0p += 32, a1p += 32) {
            const short8 a0 = *(const short8*)a0p;
            const short8 a1 = *(const short8*)a1p;
            const short8 b0 = bp0[ks * 64];
            const short8 b1 = bp1[ks * 64];
            acc00 = __builtin_amdgcn_mfma_f32_16x16x32_bf16(a0, b0, acc00, 0, 0, 0);
            acc01 = __builtin_amdgcn_mfma_f32_16x16x32_bf16(a0, b1, acc01, 0, 0, 0);
            acc10 = __builtin_amdgcn_mfma_f32_16x16x32_bf16(a1, b0, acc10, 0, 0, 0);
            acc11 = __builtin_amdgcn_mfma_f32_16x16x32_bf16(a1, b1, acc11, 0, 0, 0);
        }

        // C/D layout: col = lane&15, row = q*4 + reg
        const int c0 = 2 * wave * 16 + m;
        #pragma unroll
        for (int r = 0; r < 4; ++r) {
            const size_t row0 = (size_t)(n0 + q * 4 + r) * COUT;        // M0
            const size_t row1 = (size_t)(n0 + 16 + q * 4 + r) * COUT;   // M1
            out[row0 + c0]      = acc00[r];
            out[row0 + c0 + 16] = acc01[r];
            out[row1 + c0]      = acc10[r];
            out[row1 + c0 + 16] = acc11[r];
        }
    }
}

extern "C" void kernel_launch(void* const* d_in, const int* in_sizes, int n_in,
                              void* d_out, int out_size, void* d_ws, size_t ws_size,
                              hipStream_t stream) {
    const float* pos       = (const float*)d_in[0];
    const float* feats     = (const float*)d_in[1];
    const float* kpts      = (const float*)d_in[2];
    const float* weights   = (const float*)d_in[3];
    const int*   neighbors = (const int*)d_in[4];
    float*       out       = (float*)d_out;
    unsigned short* wTf    = (unsigned short*)d_ws;               // 245760 B
    float4* kpq            = (float4*)((char*)d_ws + WELEMS * 2); // 256 B

    wtrans_kernel<<<(WELEMS + 255) / 256, 256, 0, stream>>>(weights, kpts, wTf, kpq);
    kpconv_kernel<<<NPTS / MPTS, THREADS, 0, stream>>>(
        pos, feats, wTf, kpq, neighbors, out);
}

// Round 14
// 138.179 us; speedup vs baseline: 1.1589x; 1.1589x over previous
//
#include <hip/hip_runtime.h>

#define NPTS  65536
#define KNB   32
#define KPn   15
#define CIN   64
#define COUT  128
#define MPTS  16            // points per block (MFMA M)
#define THREADS 512         // 8 waves/block; 4 blocks/CU -> 32 waves/CU (max)
#define WSTRIDE 968         // wl row stride in bf16 elems (960 + 8 pad)
#define BCAP  48            // bucket cap per point (near-origin bursts)
#define RCAP  96            // radius-candidate cap (mean ~31 for 512 slots)
#define NTILE 8             // 128 cols / 16
#define KSTEPS 30           // 960 / 32
#define WELEMS (NTILE * KSTEPS * 64 * 8)    // 122880 bf16 elements

typedef __attribute__((ext_vector_type(8))) short short8;
typedef __attribute__((ext_vector_type(4))) float f32x4;

__device__ __forceinline__ unsigned int f2bf(float f) {
    union { float f; unsigned int i; } v; v.f = f;
    return (v.i + 0x7fffu + ((v.i >> 16) & 1u)) >> 16;   // RNE
}

// ---- prep: pack weights into MFMA B-fragment order (permuted K) + kpq/R2 ----
__global__ void wtrans_kernel(const float* __restrict__ w,
                              const float* __restrict__ kpts,
                              unsigned short* __restrict__ wTf,
                              float4* __restrict__ kpq_out) {  // [16]: 15 kpq + {R2}
    const int d = blockIdx.x * 256 + threadIdx.x;
    if (d < WELEMS) {
        const int j    = d & 7;
        const int lane = (d >> 3) & 63;
        const int ks   = (d >> 9) % KSTEPS;
        const int t    = d / (KSTEPS * 512);
        const int f    = ks * 32 + (lane >> 4) * 8 + j;
        const int cg   = f / 120;
        const int rem  = f - cg * 120;
        const int orig = (rem >> 3) * 64 + cg * 8 + (rem & 7);
        const int n    = t * 16 + (lane & 15);
        wTf[d] = (unsigned short)f2bf(w[(size_t)orig * COUT + n]);
    }
    if (blockIdx.x == 0 && threadIdx.x < 16) {
        const int k = threadIdx.x;
        if (k < KPn) {
            const float x = kpts[k * 3 + 0];
            const float y = kpts[k * 3 + 1];
            const float z = kpts[k * 3 + 2];
            kpq_out[k] = make_float4(x, y, z, x * x + y * y + z * z);
        } else {
            float mx = 0.f;
            for (int i = 0; i < KPn; ++i) {
                const float x = kpts[i * 3 + 0];
                const float y = kpts[i * 3 + 1];
                const float z = kpts[i * 3 + 2];
                mx = fmaxf(mx, x * x + y * y + z * z);
            }
            const float R = 0.1f + sqrtf(mx);
            kpq_out[15] = make_float4(R * R, 0.f, 0.f, 0.f);
        }
    }
}

__global__ __launch_bounds__(THREADS, 8) void kpconv_kernel(
    const float* __restrict__ pos,         // [N,3] f32
    const float* __restrict__ feats,       // [N,64] f32
    const unsigned short* __restrict__ wTf,// fragment-packed bf16 weights
    const float4* __restrict__ kpq_in,     // [16] precomputed kpq + R2
    const int*   __restrict__ neighbors,   // [N,32] int32
    float*       __restrict__ out)         // [N,128] f32
{
    __shared__ unsigned short wl[MPTS * WSTRIDE];  // 30976 B (permuted-K bf16)
    __shared__ unsigned int  bpk[MPTS][BCAP];      // 3 KB: (nb<<16)|(k<<12)|w12
    __shared__ int    bcnt[MPTS];
    __shared__ float  cposf[MPTS * 3];
    __shared__ float4 kpq[KPn];
    __shared__ float  rlx[RCAP], rly[RCAP], rlz[RCAP], rld[RCAP];
    __shared__ unsigned int rsl[RCAP];             // (p<<16) | nb
    __shared__ int    nact;
    __shared__ float  R2s;

    const int tid = threadIdx.x;
    const int n0  = blockIdx.x * MPTS;

    // ---- init ----
    if (tid < KPn) kpq[tid] = kpq_in[tid];
    if (tid == KPn) R2s = kpq_in[15].x;
    if (tid < MPTS) bcnt[tid] = 0;
    if (tid == THREADS - 1) nact = 0;
    if (tid < MPTS * 3) cposf[tid] = pos[(size_t)n0 * 3 + tid];
    __syncthreads();

    // ---- stage 1a-compact: radius filter, 1 slot per thread ----
    {
        const float R2 = R2s;
        const int s  = tid;                       // 512 slots = 16p x 32j
        const int p  = s >> 5;
        const int nb = neighbors[(size_t)n0 * KNB + s];
        const float rx = pos[(size_t)nb * 3 + 0] - cposf[p * 3 + 0];
        const float ry = pos[(size_t)nb * 3 + 1] - cposf[p * 3 + 1];
        const float rz = pos[(size_t)nb * 3 + 2] - cposf[p * 3 + 2];
        const float d2r = rx * rx + ry * ry + rz * rz;
        if (d2r < R2) {                           // ~6% survive
            const int idx = atomicAdd(&nact, 1);
            if (idx < RCAP) {
                rlx[idx] = rx; rly[idx] = ry; rlz[idx] = rz; rld[idx] = d2r;
                rsl[idx] = ((unsigned int)p << 16) | (unsigned int)nb;
            }
        }
    }
    __syncthreads();

    // ---- stage 1a-k: exact kernel-point test over candidates ----
    {
        const int E = min(nact, RCAP);
        for (int u = tid; u < E * 16; u += THREADS) {
            const int e = u >> 4;
            const int k = u & 15;
            if (k < KPn) {
                const float4 kp  = kpq[k];
                const float  d2r = rld[e];
                const float dot = rlx[e] * kp.x + rly[e] * kp.y + rlz[e] * kp.z;
                if (dot > 0.5f * (d2r - 0.01f + kp.w)) {
                    const float d2 = fmaxf(d2r - 2.f * dot + kp.w, 0.f);
                    const float w  = 1.0f - 10.0f * sqrtf(d2);
                    const unsigned int wq = (unsigned int)(w * 4095.0f + 0.5f);
                    const unsigned int sl = rsl[e];
                    const int p = (int)(sl >> 16);
                    const int idx = atomicAdd(&bcnt[p], 1);
                    if (idx < BCAP)
                        bpk[p][idx] = ((sl & 0xFFFFu) << 16) |
                                      ((unsigned int)k << 12) | wq;
                }
            }
        }
    }
    __syncthreads();

    // ---- stage 1b: ownership accumulation, 8 channels per work item ----
    #pragma unroll
    for (int it = 0; it < 4; ++it) {
        const int wi = tid + it * THREADS;        // 0..2047
        const int cg = wi & 7;
        const int k  = (wi >> 3) & 15;
        const int p  = wi >> 7;                   // 0..15
        if (k < KPn) {
            float a0=0.f,a1=0.f,a2=0.f,a3=0.f,a4=0.f,a5=0.f,a6=0.f,a7=0.f;
            const int cnt = min(bcnt[p], BCAP);
            for (int e = 0; e < cnt; ++e) {
                const unsigned int id = bpk[p][e];
                if (((id >> 12) & 15u) == (unsigned int)k) {
                    const float wv = (float)(id & 4095u) * (1.0f / 4095.0f);
                    const float* fr = feats + (size_t)(id >> 16) * CIN + cg * 8;
                    const float4 f0 = *(const float4*)fr;
                    const float4 f1 = *(const float4*)(fr + 4);
                    a0 += wv * f0.x; a1 += wv * f0.y; a2 += wv * f0.z; a3 += wv * f0.w;
                    a4 += wv * f1.x; a5 += wv * f1.y; a6 += wv * f1.z; a7 += wv * f1.w;
                }
            }
            uint4 u;
            u.x = f2bf(a0) | (f2bf(a1) << 16);
            u.y = f2bf(a2) | (f2bf(a3) << 16);
            u.z = f2bf(a4) | (f2bf(a5) << 16);
            u.w = f2bf(a6) | (f2bf(a7) << 16);
            *(uint4*)(wl + p * WSTRIDE + cg * 120 + k * 8) = u;   // permuted-K
        }
    }
    __syncthreads();

    // ---- stage 2: out[16][128] = wl @ W; one N-tile per wave (8 waves) ----
    {
        const int wave = tid >> 6;                // 0..7 = N-tile
        const int lane = tid & 63;
        const int m    = lane & 15;
        const int q    = lane >> 4;

        f32x4 acc = {0.f, 0.f, 0.f, 0.f};
        const unsigned short* ap = wl + m * WSTRIDE + q * 8;
        const short8* bp = (const short8*)wTf + (size_t)wave * KSTEPS * 64 + lane;

        #pragma unroll 5
        for (int ks = 0; ks < KSTEPS; ++ks, ap += 32) {
            const short8 a = *(const short8*)ap;
            const short8 b = bp[ks * 64];
            acc = __builtin_amdgcn_mfma_f32_16x16x32_bf16(a, b, acc, 0, 0, 0);
        }

        // C/D layout: col = lane&15, row = q*4 + reg
        const int c = wave * 16 + m;
        #pragma unroll
        for (int r = 0; r < 4; ++r)
            out[(size_t)(n0 + q * 4 + r) * COUT + c] = acc[r];
    }
}

extern "C" void kernel_launch(void* const* d_in, const int* in_sizes, int n_in,
                              void* d_out, int out_size, void* d_ws, size_t ws_size,
                              hipStream_t stream) {
    const float* pos       = (const float*)d_in[0];
    const float* feats     = (const float*)d_in[1];
    const float* kpts      = (const float*)d_in[2];
    const float* weights   = (const float*)d_in[3];
    const int*   neighbors = (const int*)d_in[4];
    float*       out       = (float*)d_out;
    unsigned short* wTf    = (unsigned short*)d_ws;               // 245760 B
    float4* kpq            = (float4*)((char*)d_ws + WELEMS * 2); // 256 B

    wtrans_kernel<<<(WELEMS + 255) / 256, 256, 0, stream>>>(weights, kpts, wTf, kpq);
    kpconv_kernel<<<NPTS / MPTS, THREADS, 0, stream>>>(
        pos, feats, wTf, kpq, neighbors, out);
}